// Round 4
// baseline (176.252 us; speedup 1.0000x reference)
//
#include <hip/hip_runtime.h>

// B=4, IN_C=64, IN_S=16384, OUT_C=64, OUT_S=4096, K=4.
// out[b,o,s] = bias[o,s] + sum_{i,k} x[b,i,4s+k] * w[i,k,o,s]
//
// R4: restructure for x-traffic reduction.
//   block = 256 threads = 4 waves; wave = one batch b; lane = one s.
//   Each thread accumulates 8 output channels (o0..o0+7) for its (b,s).
//   Grid = 64 s-tiles x 8 o-groups = 512 blocks (8 waves/CU).
// - x logical traffic: 8 o-group re-reads (was 32) -> 128 MB through L2.
// - w read by 4 waves of the SAME block (one per b) within a short window ->
//   L1 serves the 3 duplicates; w HBM traffic stays 256 MB (read-once).
// - XCD swizzle: 64 consecutive logical blocks (8 s-tiles x all 8 o-groups)
//   per XCD; the 8 blocks sharing an x slice are co-resident on one XCD.

__global__ __launch_bounds__(256) void adj1d_kernel(
    const float* __restrict__ x, const float* __restrict__ w,
    const float* __restrict__ bias, float* __restrict__ out) {

  int bid = blockIdx.x;                 // 0..511
  int wgid = (bid & 7) * 64 + (bid >> 3);
  int og = wgid & 7;                    // o-group: 8 output channels
  int st = wgid >> 3;                   // s-tile: 64 s values
  int lane = threadIdx.x & 63;
  int b = threadIdx.x >> 6;             // wave id = batch index
  int s = (st << 6) + lane;
  int o0 = og << 3;

  float acc[8];
  #pragma unroll
  for (int o = 0; o < 8; ++o) acc[o] = 0.f;

  const float4* __restrict__ xv = reinterpret_cast<const float4*>(x);
  // w element index: (i*4+k)*262144 + (o<<12) + s
  const float* __restrict__ wp0 = w + (o0 << 12) + s;

  #pragma unroll 2
  for (int i = 0; i < 64; ++i) {
    float4 xa4 = xv[(((b << 6) + i) << 12) + s];
    const float xa[4] = {xa4.x, xa4.y, xa4.z, xa4.w};
    #pragma unroll
    for (int k = 0; k < 4; ++k) {
      const float* wp = wp0 + (size_t)(i * 4 + k) * 262144;
      #pragma unroll
      for (int o = 0; o < 8; ++o) {
        acc[o] = fmaf(xa[k], wp[o << 12], acc[o]);
      }
    }
  }

  #pragma unroll
  for (int o = 0; o < 8; ++o) {
    float bv = bias[((o0 + o) << 12) + s];
    out[(((b << 6) + o0 + o) << 12) + s] = acc[o] + bv;
  }
}

extern "C" void kernel_launch(void* const* d_in, const int* in_sizes, int n_in,
                              void* d_out, int out_size, void* d_ws, size_t ws_size,
                              hipStream_t stream) {
  const float* x    = (const float*)d_in[0];  // (4, 64, 16384)
  const float* w    = (const float*)d_in[1];  // (64, 4, 64, 4096)
  const float* bias = (const float*)d_in[2];  // (64, 4096)
  float* out = (float*)d_out;                 // (4, 64, 4096)

  // 64 s-tiles x 8 o-groups = 512 blocks, 256 threads each
  adj1d_kernel<<<512, 256, 0, stream>>>(x, w, bias, out);
}

// Round 5
// 91.545 us; speedup vs baseline: 1.9253x; 1.9253x over previous
//
#include <hip/hip_runtime.h>

// B=4, IN_C=64, IN_S=16384, OUT_C=64, OUT_S=4096, K=4.
// out[b,o,s] = bias[o,s] + sum_{i,k} x[b,i,4s+k] * w[i,k,o,s]
//
// R5: LDS-staged x + register-prefetch pipeline.
//   block = 256 threads = 4 waves, all covering the SAME 64-s range;
//   wave = one o-pair (block covers 8 o); thread = (s=lane, 2 o, 4 b).
//   grid = 64 s-tiles x 8 o-groups = 512 blocks (2 blocks/CU, 8 waves/CU).
// - w: dword/lane, lane<->s coalesced, each element read ONCE per grid.
// - x: read ONCE per block from global (cooperative stage into LDS),
//   logical x traffic 128 MB (was 512 MB in R1); barriers keep waves
//   together so sharing is guaranteed, unlike R4's L1 hope.
// - x chunk of 4 i staged per barrier pair; next chunk prefetched into
//   registers while current chunk computes (explicit pipeline).
// - LDS readback ds_read_b128 at 16B lane stride: 2-way bank alias = free.

#define ICH 4

__global__ __launch_bounds__(256) void adj1d_kernel(
    const float* __restrict__ x, const float* __restrict__ w,
    const float* __restrict__ bias, float* __restrict__ out) {

  __shared__ float4 xs[ICH][4][64];   // [ii][b][lane] = x[b, ic+ii, 4s..4s+3], 16 KB

  int bid = blockIdx.x;               // 0..511
  // XCD swizzle: XCD = bid&7 gets wgid 0..63 = 8 s-tiles x all 8 o-groups,
  // so the 8 blocks sharing an s-tile's x slice are co-resident on one XCD.
  int wgid = (bid & 7) * 64 + (bid >> 3);
  int og = wgid & 7;                  // o-group: 8 output channels
  int st = wgid >> 3;                 // s-tile: 64 s values
  int lane = threadIdx.x & 63;
  int wv   = threadIdx.x >> 6;        // wave id: o-pair within group; also b for staging
  int sg = (st << 6) + lane;          // this thread's s
  int o0 = (og << 3) + (wv << 1);     // first of the 2 output channels

  float acc[2][4];                    // [o][b]
  #pragma unroll
  for (int o = 0; o < 2; ++o)
    #pragma unroll
    for (int b = 0; b < 4; ++b) acc[o][b] = 0.f;

  const float4* __restrict__ xv = reinterpret_cast<const float4*>(x);
  // x float4 index for (b, i, s): ((b*64 + i) << 12) + s
  // w element index: (i*4+k)*262144 + (o << 12) + s
  const float* __restrict__ wp_base = w + (o0 << 12) + sg;

  // prefetch chunk 0 (this wave stages batch b = wv)
  float4 pf[ICH];
  #pragma unroll
  for (int ii = 0; ii < ICH; ++ii)
    pf[ii] = xv[(((wv << 6) + ii) << 12) + sg];

  for (int ic = 0; ic < 64; ic += ICH) {
    __syncthreads();                  // prior chunk's reads complete
    #pragma unroll
    for (int ii = 0; ii < ICH; ++ii) xs[ii][wv][lane] = pf[ii];
    __syncthreads();                  // chunk staged

    if (ic + ICH < 64) {              // prefetch next chunk (hides under compute)
      #pragma unroll
      for (int ii = 0; ii < ICH; ++ii)
        pf[ii] = xv[(((wv << 6) + (ic + ICH + ii)) << 12) + sg];
    }

    #pragma unroll
    for (int ii = 0; ii < ICH; ++ii) {
      float xk[4][4];                 // [b][k]
      #pragma unroll
      for (int b = 0; b < 4; ++b) {
        float4 xb = xs[ii][b][lane];  // ds_read_b128
        xk[b][0] = xb.x; xk[b][1] = xb.y; xk[b][2] = xb.z; xk[b][3] = xb.w;
      }
      const float* wp = wp_base + (ic + ii) * 1048576;  // (i*4+0)*262144
      #pragma unroll
      for (int k = 0; k < 4; ++k) {
        float w0 = wp[0];
        float w1 = wp[4096];
        #pragma unroll
        for (int b = 0; b < 4; ++b) {
          acc[0][b] = fmaf(xk[b][k], w0, acc[0][b]);
          acc[1][b] = fmaf(xk[b][k], w1, acc[1][b]);
        }
        wp += 262144;
      }
    }
  }

  float b0 = bias[(o0 << 12) + sg];
  float b1 = bias[((o0 + 1) << 12) + sg];
  #pragma unroll
  for (int b = 0; b < 4; ++b) {
    out[(((b << 6) + o0)     << 12) + sg] = acc[0][b] + b0;
    out[(((b << 6) + o0 + 1) << 12) + sg] = acc[1][b] + b1;
  }
}

extern "C" void kernel_launch(void* const* d_in, const int* in_sizes, int n_in,
                              void* d_out, int out_size, void* d_ws, size_t ws_size,
                              hipStream_t stream) {
  const float* x    = (const float*)d_in[0];  // (4, 64, 16384)
  const float* w    = (const float*)d_in[1];  // (64, 4, 64, 4096)
  const float* bias = (const float*)d_in[2];  // (64, 4096)
  float* out = (float*)d_out;                 // (4, 64, 4096)

  // 64 s-tiles x 8 o-groups = 512 blocks, 256 threads each
  adj1d_kernel<<<512, 256, 0, stream>>>(x, w, bias, out);
}